// Round 1
// baseline (623.760 us; speedup 1.0000x reference)
//
#include <hip/hip_runtime.h>
#include <hip/hip_bf16.h>

// Problem constants (fixed by the reference)
#define S_SAMPLES 4096
#define NAG 16
#define DDIM 64
#define RDIM 32

__device__ __forceinline__ float tanh_fast(float x) {
    float ax = fabsf(x);
    float e  = __expf(-2.0f * ax);                       // v_exp_f32
    float t  = (1.0f - e) * __builtin_amdgcn_rcpf(1.0f + e);
    return copysignf(t, x);
}

__device__ __forceinline__ float4 ld4(const float* p) {
    return *reinterpret_cast<const float4*>(p);
}

#define DOT4(A, V, ACC) \
    ACC = fmaf((A).x, (V).x, fmaf((A).y, (V).y, fmaf((A).z, (V).z, fmaf((A).w, (V).w, ACC))))

__global__ __launch_bounds__(256, 2) void att_mask_kernel(
    const float* __restrict__ x, const float* __restrict__ L,
    const float* __restrict__ Aq, const float* __restrict__ Ak,
    const float* __restrict__ Av, const float* __restrict__ Ao,
    float* __restrict__ out)
{
    // LDS: 72,896 B total -> 2 blocks/CU
    __shared__ alignas(16) float sA[3][32][68];   // A row-major, stride 68 (b128-aligned, 2-way banks)
    __shared__ alignas(16) float sAo[32];
    __shared__ alignas(16) float sX[4][16 * 68];  // per-wave x^T [n][d], stride 68
    __shared__ alignas(16) float sQ[4][32 * 17];  // per-wave Q [r][n] stride 17; reused as o [r][n]
    __shared__ alignas(16) float sKt[4][16 * 36]; // per-wave K^T [n][s] stride 36 (144B rows, b128 ok)
    __shared__ alignas(16) float sV[4][32 * 20];  // per-wave V [s][n] stride 20 (80B rows, b128 ok)
    __shared__ alignas(16) float sRsq[16 * 17];   // R^2 tile for this sample

    const int tid  = threadIdx.x;
    const int lane = tid & 63;
    const int w    = tid >> 6;
    const int s_idx = blockIdx.x;

    // ---- one-time: stage A matrices + Ao into LDS ----
    for (int idx = tid; idx < 3 * 2048; idx += 256) {
        int m = idx >> 11;            // uniform per iteration (256 | 2048)
        int e = idx & 2047;
        const float* Am = (m == 0) ? Aq : (m == 1) ? Ak : Av;
        sA[m][e >> 6][e & 63] = Am[e];
    }
    if (tid < 32) sAo[tid] = Ao[tid];
    __syncthreads();

    float* xw  = sX[w];
    float* qw  = sQ[w];
    float* ktw = sKt[w];
    float* vw  = sV[w];

    for (int t = 0; t < 4; ++t) {
        const int i_loc = w * 4 + t;          // row index within the sample
        const int b     = s_idx * NAG + i_loc;

        // ---- stage x[b] (fp32, [64][16]) into LDS transposed x^T[n][d] ----
        const float4* xg4 = reinterpret_cast<const float4*>(x) + (size_t)b * 256;
        #pragma unroll
        for (int it = 0; it < 4; ++it) {
            int f4 = it * 64 + lane;
            float4 v = xg4[f4];               // coalesced 1KB/instr
            int d  = f4 >> 2;
            int n0 = (f4 & 3) << 2;
            xw[(n0 + 0) * 68 + d] = v.x;
            xw[(n0 + 1) * 68 + d] = v.y;
            xw[(n0 + 2) * 68 + d] = v.z;
            xw[(n0 + 3) * 68 + d] = v.w;
        }

        // ---- num_neighbors from L[b,0,:] ----
        float lv = (lane < 16) ? L[(size_t)b * 256 + lane] : 0.0f;
        unsigned long long ball = __ballot(lv >= 1.0f);
        float scale = rsqrtf((float)(__popcll(ball) + 1));

        __syncthreads();

        // ---- QKV: Q/K/V[r][n] = tanh(sum_d A[r][d] * x[d][n]) ----
        const int c  = lane & 3;              // n in {c, c+4, c+8, c+12}
        const int rr = lane >> 2;             // r in {rr, rr+16}
        float acc[3][2][4];
        #pragma unroll
        for (int m = 0; m < 3; ++m)
            #pragma unroll
            for (int h = 0; h < 2; ++h)
                #pragma unroll
                for (int j = 0; j < 4; ++j) acc[m][h][j] = 0.0f;

        #pragma unroll
        for (int d = 0; d < 64; d += 4) {
            float4 xv0 = ld4(&xw[(c     ) * 68 + d]);
            float4 xv1 = ld4(&xw[(c +  4) * 68 + d]);
            float4 xv2 = ld4(&xw[(c +  8) * 68 + d]);
            float4 xv3 = ld4(&xw[(c + 12) * 68 + d]);
            #pragma unroll
            for (int m = 0; m < 3; ++m) {
                float4 a0 = ld4(&sA[m][rr     ][d]);
                float4 a1 = ld4(&sA[m][rr + 16][d]);
                DOT4(a0, xv0, acc[m][0][0]); DOT4(a0, xv1, acc[m][0][1]);
                DOT4(a0, xv2, acc[m][0][2]); DOT4(a0, xv3, acc[m][0][3]);
                DOT4(a1, xv0, acc[m][1][0]); DOT4(a1, xv1, acc[m][1][1]);
                DOT4(a1, xv2, acc[m][1][2]); DOT4(a1, xv3, acc[m][1][3]);
            }
        }

        #pragma unroll
        for (int h = 0; h < 2; ++h)
            #pragma unroll
            for (int j = 0; j < 4; ++j) {
                int r = rr + 16 * h;
                int n = c + 4 * j;
                qw[r * 17 + n]  = tanh_fast(acc[0][h][j]);   // Q row-major
                ktw[n * 36 + r] = tanh_fast(acc[1][h][j]);   // K transposed [n][s]
                vw[r * 20 + n]  = tanh_fast(acc[2][h][j]);   // V row-major
            }
        __syncthreads();

        // ---- scores[r][s] = sum_n Q[r][n] K[s][n]; lane covers (r, half of s) ----
        const int r_s = lane & 31;
        const int sh  = lane >> 5;
        float sc[16];
        #pragma unroll
        for (int j = 0; j < 16; ++j) sc[j] = 0.0f;

        #pragma unroll 4
        for (int n = 0; n < 16; ++n) {
            float qv = qw[r_s * 17 + n];
            const float* kr = &ktw[n * 36 + sh * 16];
            float4 k0 = ld4(kr + 0), k1 = ld4(kr + 4), k2 = ld4(kr + 8), k3 = ld4(kr + 12);
            sc[ 0] = fmaf(qv, k0.x, sc[ 0]); sc[ 1] = fmaf(qv, k0.y, sc[ 1]);
            sc[ 2] = fmaf(qv, k0.z, sc[ 2]); sc[ 3] = fmaf(qv, k0.w, sc[ 3]);
            sc[ 4] = fmaf(qv, k1.x, sc[ 4]); sc[ 5] = fmaf(qv, k1.y, sc[ 5]);
            sc[ 6] = fmaf(qv, k1.z, sc[ 6]); sc[ 7] = fmaf(qv, k1.w, sc[ 7]);
            sc[ 8] = fmaf(qv, k2.x, sc[ 8]); sc[ 9] = fmaf(qv, k2.y, sc[ 9]);
            sc[10] = fmaf(qv, k2.z, sc[10]); sc[11] = fmaf(qv, k2.w, sc[11]);
            sc[12] = fmaf(qv, k3.x, sc[12]); sc[13] = fmaf(qv, k3.y, sc[13]);
            sc[14] = fmaf(qv, k3.z, sc[14]); sc[15] = fmaf(qv, k3.w, sc[15]);
        }

        // ---- softmax over s (32 values: 16 local + partner lane via xor 32) ----
        #pragma unroll
        for (int j = 0; j < 16; ++j) sc[j] *= scale;
        float mx = sc[0];
        #pragma unroll
        for (int j = 1; j < 16; ++j) mx = fmaxf(mx, sc[j]);
        mx = fmaxf(mx, __shfl_xor(mx, 32, 64));
        float sum = 0.0f;
        #pragma unroll
        for (int j = 0; j < 16; ++j) { sc[j] = __expf(sc[j] - mx); sum += sc[j]; }
        sum += __shfl_xor(sum, 32, 64);
        float inv = __builtin_amdgcn_rcpf(sum);
        #pragma unroll
        for (int j = 0; j < 16; ++j) sc[j] *= inv;

        // ---- o[r][n] = sum_s attn[r][s] V[s][n] (partial over this lane's s half) ----
        float on[16];
        #pragma unroll
        for (int n = 0; n < 16; ++n) on[n] = 0.0f;
        #pragma unroll 4
        for (int j = 0; j < 16; ++j) {
            const float* vr = &vw[(sh * 16 + j) * 20];
            float p = sc[j];
            float4 v0 = ld4(vr + 0), v1 = ld4(vr + 4), v2 = ld4(vr + 8), v3 = ld4(vr + 12);
            on[ 0] = fmaf(p, v0.x, on[ 0]); on[ 1] = fmaf(p, v0.y, on[ 1]);
            on[ 2] = fmaf(p, v0.z, on[ 2]); on[ 3] = fmaf(p, v0.w, on[ 3]);
            on[ 4] = fmaf(p, v1.x, on[ 4]); on[ 5] = fmaf(p, v1.y, on[ 5]);
            on[ 6] = fmaf(p, v1.z, on[ 6]); on[ 7] = fmaf(p, v1.w, on[ 7]);
            on[ 8] = fmaf(p, v2.x, on[ 8]); on[ 9] = fmaf(p, v2.y, on[ 9]);
            on[10] = fmaf(p, v2.z, on[10]); on[11] = fmaf(p, v2.w, on[11]);
            on[12] = fmaf(p, v3.x, on[12]); on[13] = fmaf(p, v3.y, on[13]);
            on[14] = fmaf(p, v3.z, on[14]); on[15] = fmaf(p, v3.w, on[15]);
        }
        #pragma unroll
        for (int n = 0; n < 16; ++n) on[n] += __shfl_xor(on[n], 32, 64);

        __syncthreads();                       // all Q reads done before reuse as o
        if (sh == 0) {
            #pragma unroll
            for (int n = 0; n < 16; ++n) qw[r_s * 17 + n] = on[n];
        }
        __syncthreads();

        // ---- R[n] = tanh(sum_r Ao[r] o[r][n]); store R^2 into sample tile ----
        if (lane < 16) {
            float accR = 0.0f;
            #pragma unroll
            for (int r2 = 0; r2 < 32; ++r2)
                accR = fmaf(sAo[r2], qw[r2 * 17 + lane], accR);
            float tt = tanh_fast(accR);
            sRsq[i_loc * 17 + lane] = tt * tt;
        }
        __syncthreads();
    }

    // ---- Laplacian-like reconstruction: diag = full row-sum of R^2, offdiag = -R^2 ----
    {
        int i = tid >> 4, j = tid & 15;
        float rij = sRsq[i * 17 + j];
        float srow = 0.0f;
        #pragma unroll
        for (int k = 0; k < 16; ++k) srow += sRsq[i * 17 + k];
        out[(size_t)s_idx * 256 + tid] = (i == j) ? srow : -rij;
    }
}

extern "C" void kernel_launch(void* const* d_in, const int* in_sizes, int n_in,
                              void* d_out, int out_size, void* d_ws, size_t ws_size,
                              hipStream_t stream) {
    const float* x  = (const float*)d_in[0];
    const float* L  = (const float*)d_in[1];
    const float* Aq = (const float*)d_in[2];
    const float* Ak = (const float*)d_in[3];
    const float* Av = (const float*)d_in[4];
    const float* Ao = (const float*)d_in[5];
    float* out = (float*)d_out;

    dim3 grid(S_SAMPLES), block(256);
    hipLaunchKernelGGL(att_mask_kernel, grid, block, 0, stream,
                       x, L, Aq, Ak, Av, Ao, out);
}

// Round 3
// 399.161 us; speedup vs baseline: 1.5627x; 1.5627x over previous
//
#include <hip/hip_runtime.h>
#include <hip/hip_bf16.h>

#define S_SAMPLES 4096
#define NAG 16

typedef __attribute__((ext_vector_type(8))) short short8;   // 8 bf16 = 4 VGPRs (MFMA A/B frag)
typedef __attribute__((ext_vector_type(4))) float f32x4;    // MFMA C/D frag

union F8 { short8 v; unsigned u[4]; };

__device__ __forceinline__ float tanh_fast(float x) {
    float ax = fabsf(x);
    float e  = __expf(-2.0f * ax);
    float t  = (1.0f - e) * __builtin_amdgcn_rcpf(1.0f + e);
    return copysignf(t, x);
}

__device__ __forceinline__ unsigned pk2(float a, float b) {
    float2 f; f.x = a; f.y = b;
    __hip_bfloat162 h = __float22bfloat162_rn(f);
    unsigned r; __builtin_memcpy(&r, &h, 4); return r;
}

__device__ __forceinline__ short bfs(float a) {
    __hip_bfloat16 h = __float2bfloat16(a);
    short r; __builtin_memcpy(&r, &h, 2); return r;
}

__device__ __forceinline__ float4 ld4(const float* p) {
    return *reinterpret_cast<const float4*>(p);
}

// Row stride for all bf16 LDS tiles: 40 shorts = 80 B (16B-multiple for b128,
// and 20*r % 32 bank pattern spreads starts across rows).
#define STR 40

__global__ __launch_bounds__(256, 2) void att_mask_kernel(
    const float* __restrict__ x, const float* __restrict__ L,
    const float* __restrict__ Aq, const float* __restrict__ Ak,
    const float* __restrict__ Av, const float* __restrict__ Ao,
    float* __restrict__ out)
{
    // Per-wave bf16 scratch (no cross-wave sharing except sRsq)
    __shared__ alignas(16) short sQ [4][32 * STR];  // Q[r][n], n zero-padded 16..31
    __shared__ alignas(16) short sK [4][32 * STR];  // K[s][n], zero-padded
    __shared__ alignas(16) short sVt[4][16 * STR];  // V^T[n][s], s=0..31
    __shared__ alignas(16) short sAt[4][32 * STR];  // attn[r][s]
    __shared__ alignas(16) float sRsq[16 * 17];

    const int tid  = threadIdx.x;
    const int lane = tid & 63;
    const int w    = tid >> 6;
    const int c4   = lane & 15;       // n / col index
    const int q    = lane >> 4;       // quad
    const int s_idx = blockIdx.x;

    short* qw = sQ[w];  short* kw = sK[w];  short* vtw = sVt[w];  short* atw = sAt[w];

    // ---- one-time: A-matrix MFMA A-fragments (reg-resident) ----
    // A_frag[m][rh][kb]: lane holds Amat[r = c4+16rh][d = 32kb + 8q + j], j=0..7
    F8 aF[3][2][2];
    {
        const float* mats[3] = { Aq, Ak, Av };
        #pragma unroll
        for (int m = 0; m < 3; ++m)
            #pragma unroll
            for (int rh = 0; rh < 2; ++rh)
                #pragma unroll
                for (int kb = 0; kb < 2; ++kb) {
                    const float* p = mats[m] + (c4 + 16 * rh) * 64 + 32 * kb + 8 * q;
                    float4 a0 = ld4(p), a1 = ld4(p + 4);
                    aF[m][rh][kb].u[0] = pk2(a0.x, a0.y);
                    aF[m][rh][kb].u[1] = pk2(a0.z, a0.w);
                    aF[m][rh][kb].u[2] = pk2(a1.x, a1.y);
                    aF[m][rh][kb].u[3] = pk2(a1.z, a1.w);
                }
    }
    // Ao values matching the o C-fragment rows r = 4q+reg+16rh
    float4 ao0 = ld4(Ao + 4 * q);
    float4 ao1 = ld4(Ao + 16 + 4 * q);

    // ---- zero-fill Q/K pad columns n=16..31 (read by scores MFMA K-dim) ----
    {
        int r = lane & 31, hh = lane >> 5;
        uint2 z; z.x = 0; z.y = 0;
        *reinterpret_cast<uint2*>(&qw[r * STR + 16 + 8 * hh]) = z;
        *reinterpret_cast<uint2*>(&qw[r * STR + 20 + 8 * hh]) = z;
        *reinterpret_cast<uint2*>(&kw[r * STR + 16 + 8 * hh]) = z;
        *reinterpret_cast<uint2*>(&kw[r * STR + 20 + 8 * hh]) = z;
    }

    const f32x4 zz = {0.f, 0.f, 0.f, 0.f};

    for (int t = 0; t < 4; ++t) {
        const int i_loc = w * 4 + t;
        const int b     = s_idx * NAG + i_loc;

        // ---- num_neighbors ----
        float lv = (lane < 16) ? L[(size_t)b * 256 + lane] : 0.0f;
        unsigned long long ball = __ballot(lv >= 1.0f);
        float scale = rsqrtf((float)(__popcll(ball) + 1));

        // ---- x directly into B-fragments: lane needs x[d=32kb+8q+j][n=c4] ----
        const float* xb = x + (size_t)b * 1024 + 128 * q + c4;
        float xv[2][8];
        #pragma unroll
        for (int kb = 0; kb < 2; ++kb)
            #pragma unroll
            for (int j = 0; j < 8; ++j)
                xv[kb][j] = xb[512 * kb + 16 * j];
        F8 bx[2];
        #pragma unroll
        for (int kb = 0; kb < 2; ++kb)
            #pragma unroll
            for (int p = 0; p < 4; ++p)
                bx[kb].u[p] = pk2(xv[kb][2 * p], xv[kb][2 * p + 1]);

        // ---- QKV: 12 MFMAs ----
        f32x4 accQ[2], accK[2], accV[2];
        #pragma unroll
        for (int rh = 0; rh < 2; ++rh) {
            accQ[rh] = __builtin_amdgcn_mfma_f32_16x16x32_bf16(aF[0][rh][0].v, bx[0].v, zz, 0, 0, 0);
            accQ[rh] = __builtin_amdgcn_mfma_f32_16x16x32_bf16(aF[0][rh][1].v, bx[1].v, accQ[rh], 0, 0, 0);
            accK[rh] = __builtin_amdgcn_mfma_f32_16x16x32_bf16(aF[1][rh][0].v, bx[0].v, zz, 0, 0, 0);
            accK[rh] = __builtin_amdgcn_mfma_f32_16x16x32_bf16(aF[1][rh][1].v, bx[1].v, accK[rh], 0, 0, 0);
            accV[rh] = __builtin_amdgcn_mfma_f32_16x16x32_bf16(aF[2][rh][0].v, bx[0].v, zz, 0, 0, 0);
            accV[rh] = __builtin_amdgcn_mfma_f32_16x16x32_bf16(aF[2][rh][1].v, bx[1].v, accV[rh], 0, 0, 0);
        }

        // ---- tanh + stage to LDS (C-frag: row r=4q+reg+16rh, col n=c4) ----
        #pragma unroll
        for (int rh = 0; rh < 2; ++rh) {
            float tq[4], tk[4], tv[4];
            #pragma unroll
            for (int r2 = 0; r2 < 4; ++r2) {
                tq[r2] = tanh_fast(accQ[rh][r2]);
                tk[r2] = tanh_fast(accK[rh][r2]);
                tv[r2] = tanh_fast(accV[rh][r2]);
            }
            #pragma unroll
            for (int r2 = 0; r2 < 4; ++r2) {
                int r = 4 * q + r2 + 16 * rh;
                qw[r * STR + c4] = bfs(tq[r2]);
                kw[r * STR + c4] = bfs(tk[r2]);
            }
            uint2 vpk; vpk.x = pk2(tv[0], tv[1]); vpk.y = pk2(tv[2], tv[3]);
            *reinterpret_cast<uint2*>(&vtw[c4 * STR + 4 * q + 16 * rh]) = vpk;  // V^T[n=c4][s..s+3]
        }
        __syncthreads();

        // ---- scoresT[s][r] = sum_n K[s][n] Q[r][n]  (K-dim n padded to 32) ----
        short8 kfrag[2], qfrag[2];
        #pragma unroll
        for (int hh = 0; hh < 2; ++hh) {
            kfrag[hh] = *reinterpret_cast<const short8*>(&kw[(c4 + 16 * hh) * STR + 8 * q]);
            qfrag[hh] = *reinterpret_cast<const short8*>(&qw[(c4 + 16 * hh) * STR + 8 * q]);
        }
        f32x4 sc[2][2];   // [sh][rh2]: scT[s=4q+reg+16sh][r=c4+16rh2]
        #pragma unroll
        for (int sh = 0; sh < 2; ++sh)
            #pragma unroll
            for (int rh2 = 0; rh2 < 2; ++rh2)
                sc[sh][rh2] = __builtin_amdgcn_mfma_f32_16x16x32_bf16(kfrag[sh], qfrag[rh2], zz, 0, 0, 0);

        // ---- softmax over s per row r=c4+16rh2 (8 local + quads via xor16/32) ----
        #pragma unroll
        for (int rh2 = 0; rh2 < 2; ++rh2) {
            float v[8];
            #pragma unroll
            for (int sh = 0; sh < 2; ++sh)
                #pragma unroll
                for (int r2 = 0; r2 < 4; ++r2)
                    v[sh * 4 + r2] = sc[sh][rh2][r2] * scale;
            float mx = v[0];
            #pragma unroll
            for (int j2 = 1; j2 < 8; ++j2) mx = fmaxf(mx, v[j2]);
            mx = fmaxf(mx, __shfl_xor(mx, 16));
            mx = fmaxf(mx, __shfl_xor(mx, 32));
            float sum = 0.f;
            #pragma unroll
            for (int j2 = 0; j2 < 8; ++j2) { v[j2] = __expf(v[j2] - mx); sum += v[j2]; }
            sum += __shfl_xor(sum, 16);
            sum += __shfl_xor(sum, 32);
            float inv = __builtin_amdgcn_rcpf(sum);
            #pragma unroll
            for (int sh = 0; sh < 2; ++sh)
                #pragma unroll
                for (int r2 = 0; r2 < 4; ++r2)
                    sc[sh][rh2][r2] = v[sh * 4 + r2] * inv;
        }

        // ---- attn[r][s] to LDS: rows r=c4+16rh2, s = 4q+16sh+{0..3} ----
        #pragma unroll
        for (int rh2 = 0; rh2 < 2; ++rh2)
            #pragma unroll
            for (int sh = 0; sh < 2; ++sh) {
                uint2 ap; ap.x = pk2(sc[sh][rh2][0], sc[sh][rh2][1]);
                ap.y = pk2(sc[sh][rh2][2], sc[sh][rh2][3]);
                *reinterpret_cast<uint2*>(&atw[(c4 + 16 * rh2) * STR + 4 * q + 16 * sh]) = ap;
            }
        __syncthreads();

        // ---- PV: o[r][n] = sum_s attn[r][s] V[s][n]  (2 MFMAs, K=s=32) ----
        short8 vfrag = *reinterpret_cast<const short8*>(&vtw[c4 * STR + 8 * q]);
        f32x4 o[2];
        #pragma unroll
        for (int rh = 0; rh < 2; ++rh) {
            short8 afr = *reinterpret_cast<const short8*>(&atw[(c4 + 16 * rh) * STR + 8 * q]);
            o[rh] = __builtin_amdgcn_mfma_f32_16x16x32_bf16(afr, vfrag, zz, 0, 0, 0);
        }

        // ---- R[n] = tanh(sum_r Ao[r] o[r][n]); rows of lane: r = 4q+reg+16rh ----
        float part = 0.f;
        part = fmaf(ao0.x, o[0][0], part); part = fmaf(ao0.y, o[0][1], part);
        part = fmaf(ao0.z, o[0][2], part); part = fmaf(ao0.w, o[0][3], part);
        part = fmaf(ao1.x, o[1][0], part); part = fmaf(ao1.y, o[1][1], part);
        part = fmaf(ao1.z, o[1][2], part); part = fmaf(ao1.w, o[1][3], part);
        part += __shfl_xor(part, 16);
        part += __shfl_xor(part, 32);
        if (lane < 16) {
            float tt = tanh_fast(part);
            sRsq[i_loc * 17 + lane] = tt * tt;
        }
        __syncthreads();
    }

    // ---- Laplacian-like reconstruction ----
    {
        int i = tid >> 4, j = tid & 15;
        float rij = sRsq[i * 17 + j];
        float srow = 0.0f;
        #pragma unroll
        for (int k = 0; k < 16; ++k) srow += sRsq[i * 17 + k];
        out[(size_t)s_idx * 256 + tid] = (i == j) ? srow : -rij;
    }
}

extern "C" void kernel_launch(void* const* d_in, const int* in_sizes, int n_in,
                              void* d_out, int out_size, void* d_ws, size_t ws_size,
                              hipStream_t stream) {
    const float* x  = (const float*)d_in[0];
    const float* L  = (const float*)d_in[1];
    const float* Aq = (const float*)d_in[2];
    const float* Ak = (const float*)d_in[3];
    const float* Av = (const float*)d_in[4];
    const float* Ao = (const float*)d_in[5];
    float* out = (float*)d_out;

    dim3 grid(S_SAMPLES), block(256);
    hipLaunchKernelGGL(att_mask_kernel, grid, block, 0, stream,
                       x, L, Aq, Ak, Av, Ao, out);
}